// Round 13
// baseline (296.538 us; speedup 1.0000x reference)
//
#include <hip/hip_runtime.h>

#define DIN  32
#define DH   64
#define DOUT 16
#define BKT_SHIFT 9         // 512 nodes per bucket
#define BKT_NODES 512
#define MAXBKT 256          // supports N <= 131072 (also needed for 17-bit src pack)
#define PBLK 256            // partition blocks (hist/part grids must match)
#define SRC_BITS 17
#define SRC_MASK ((1u << SRC_BITS) - 1u)

// ---- 1. per-block LDS histogram of dst buckets ------------------------------
__global__ void k_hist(const int* __restrict__ dst, int* __restrict__ hist,
                       int E, int NBKT) {
    __shared__ int h[MAXBKT];
    int tid = threadIdx.x;
    for (int i = tid; i < NBKT; i += blockDim.x) h[i] = 0;
    __syncthreads();
    int nth = gridDim.x * blockDim.x;
    int EV = E >> 2;
    const int4* d4p = (const int4*)dst;
    for (int v = blockIdx.x * blockDim.x + tid; v < EV; v += nth) {
        int4 d = d4p[v];
        atomicAdd(&h[d.x >> BKT_SHIFT], 1);
        atomicAdd(&h[d.y >> BKT_SHIFT], 1);
        atomicAdd(&h[d.z >> BKT_SHIFT], 1);
        atomicAdd(&h[d.w >> BKT_SHIFT], 1);
    }
    if (blockIdx.x == 0 && tid < (E & 3))
        atomicAdd(&h[dst[(E & ~3) + tid] >> BKT_SHIFT], 1);
    __syncthreads();
    for (int i = tid; i < NBKT; i += blockDim.x)
        hist[i * PBLK + blockIdx.x] = h[i];
}

// ---- 2. scan hist (bucket-major) -> per-(block,bucket) offsets + bucketBase -
__global__ void k_scanhist(int* __restrict__ hist, int* __restrict__ bucketBase,
                           int total, int NBKT, int E) {
    __shared__ int s[1024];
    int tid = threadIdx.x;
    int chunk = (total + 1023) >> 10;
    int lo = tid * chunk, hi = min(total, lo + chunk);
    int sum = 0;
    for (int i = lo; i < hi; ++i) sum += hist[i];
    s[tid] = sum;
    __syncthreads();
    for (int off = 1; off < 1024; off <<= 1) {
        int t = (tid >= off) ? s[tid - off] : 0;
        __syncthreads();
        s[tid] += t;
        __syncthreads();
    }
    int run = s[tid] - sum;   // exclusive prefix of this chunk
    for (int i = lo; i < hi; ++i) {
        int v = hist[i];
        if ((i & (PBLK - 1)) == 0) bucketBase[i / PBLK] = run;  // bucket column start
        hist[i] = run;
        run += v;
    }
    if (tid == 0) bucketBase[NBKT] = E;
}

// ---- 3. partition PACKED pairs into buckets via block-private LDS cursors ---
// pack = (dst & 511) << 17 | src  (4B/edge, halves part-write + build-read).
// Each (block,bucket) subrange is private -> frontier lines on one CU/XCD,
// filled within the block's pass: write amplification ~1 by construction.
__global__ void k_part(const int* __restrict__ src, const int* __restrict__ dst,
                       const int* __restrict__ hist, unsigned* __restrict__ pairs,
                       int E, int NBKT) {
    __shared__ int cur[MAXBKT];
    int tid = threadIdx.x;
    for (int i = tid; i < NBKT; i += blockDim.x)
        cur[i] = hist[i * PBLK + blockIdx.x];
    __syncthreads();
    int nth = gridDim.x * blockDim.x;
    int EV = E >> 2;
    const int4* d4p = (const int4*)dst;
    const int4* s4p = (const int4*)src;
    for (int v = blockIdx.x * blockDim.x + tid; v < EV; v += nth) {
        int4 d = d4p[v];
        int4 s = s4p[v];
        int p;
        p = atomicAdd(&cur[d.x >> BKT_SHIFT], 1);
        pairs[p] = ((unsigned)(d.x & (BKT_NODES - 1)) << SRC_BITS) | (unsigned)s.x;
        p = atomicAdd(&cur[d.y >> BKT_SHIFT], 1);
        pairs[p] = ((unsigned)(d.y & (BKT_NODES - 1)) << SRC_BITS) | (unsigned)s.y;
        p = atomicAdd(&cur[d.z >> BKT_SHIFT], 1);
        pairs[p] = ((unsigned)(d.z & (BKT_NODES - 1)) << SRC_BITS) | (unsigned)s.z;
        p = atomicAdd(&cur[d.w >> BKT_SHIFT], 1);
        pairs[p] = ((unsigned)(d.w & (BKT_NODES - 1)) << SRC_BITS) | (unsigned)s.w;
    }
    if (blockIdx.x == 0 && tid < (E & 3)) {
        int e = (E & ~3) + tid;
        int d = dst[e];
        int p = atomicAdd(&cur[d >> BKT_SHIFT], 1);
        pairs[p] = ((unsigned)(d & (BKT_NODES - 1)) << SRC_BITS) | (unsigned)src[e];
    }
}

// ---- 4. per-bucket CSR finalize + fused xg scale ----------------------------
// count -> LDS scan -> emit rowStart/deg/dinv -> scale this bucket's x slab
// (fused k_xg; block-local 64KB stream) -> place edgeSrc in private window.
__global__ void k_build(const unsigned* __restrict__ pairs,
                        const int* __restrict__ bucketBase,
                        int* __restrict__ rowStart, int* __restrict__ deg,
                        float* __restrict__ dinv, int* __restrict__ edgeSrc,
                        const float4* __restrict__ x4, float4* __restrict__ xg4,
                        int N, int NBKT) {
    __shared__ int cnt[BKT_NODES];   // 2KB counts (preserved for deg/dinv/xg)
    __shared__ int loc[BKT_NODES];   // 2KB start offsets -> reused as cursors
    __shared__ int s[BKT_NODES];     // 2KB scan
    int b = blockIdx.x;
    int n_lo = b << BKT_SHIFT;
    int nNodes = min(N - n_lo, BKT_NODES);
    int segBase = bucketBase[b];
    int segLen  = bucketBase[b + 1] - segBase;
    int tid = threadIdx.x;   // blockDim = BKT_NODES (512)

    cnt[tid] = 0;
    __syncthreads();
    for (int t = tid; t < segLen; t += BKT_NODES)
        atomicAdd(&cnt[pairs[segBase + t] >> SRC_BITS], 1);
    __syncthreads();
    // exclusive scan of cnt (one element per thread)
    int c = cnt[tid];
    s[tid] = c;
    __syncthreads();
    for (int off = 1; off < BKT_NODES; off <<= 1) {
        int t = (tid >= off) ? s[tid - off] : 0;
        __syncthreads();
        s[tid] += t;
        __syncthreads();
    }
    loc[tid] = s[tid] - c;
    // emit rowStart / deg / dinv (coalesced)
    if (tid < nNodes) {
        rowStart[n_lo + tid] = segBase + (s[tid] - c);
        deg[n_lo + tid]      = c;
        dinv[n_lo + tid]     = rsqrtf((float)c + 1.0f);  // +1 self-loop
    }
    __syncthreads();
    // fused xg scale: this bucket's x slab (nNodes x 32 floats, block-local)
    for (int i = tid; i < nNodes * 8; i += BKT_NODES) {
        float dv = rsqrtf((float)cnt[i >> 3] + 1.0f);
        float4 v = x4[(size_t)n_lo * 8 + i];
        v.x *= dv; v.y *= dv; v.z *= dv; v.w *= dv;
        xg4[(size_t)n_lo * 8 + i] = v;
    }
    // place edges within the block-private window (loc doubles as cursor)
    for (int t = tid; t < segLen; t += BKT_NODES) {
        unsigned pk = pairs[segBase + t];
        int p = atomicAdd(&loc[pk >> SRC_BITS], 1);
        edgeSrc[segBase + p] = (int)(pk & SRC_MASK);
    }
}

// ---- layer-1 aggregation: s_i = sum_j xg_j + xg_i ---------------------------
// wave per node. lane = es*8 + fl. Two-stage predicated block (2 latency hops).
__global__ void k_agg1(const int* __restrict__ rowStart, const int* __restrict__ deg,
                       const int* __restrict__ edgeSrc, const float4* __restrict__ xg4,
                       float4* __restrict__ s4, int N) {
    int tid = threadIdx.x;
    int w = tid >> 6, lane = tid & 63;
    int es = lane >> 3, fl = lane & 7;
    int node = blockIdx.x * 4 + w;   // wave-uniform
    if (node >= N) return;

    int s = rowStart[node], c = deg[node];
    float4 a0 = {0,0,0,0}, a1 = {0,0,0,0}, a2 = {0,0,0,0}, a3 = {0,0,0,0};
    int j0 = 0, j1 = 0, j2 = 0, j3 = 0;
    int o0 = es, o1 = 8 + es, o2 = 16 + es, o3 = 24 + es;
    if (o0 < c) j0 = edgeSrc[s + o0];
    if (o1 < c) j1 = edgeSrc[s + o1];
    if (o2 < c) j2 = edgeSrc[s + o2];
    if (o3 < c) j3 = edgeSrc[s + o3];
    if (o0 < c) a0 = xg4[(size_t)j0 * 8 + fl];
    if (o1 < c) a1 = xg4[(size_t)j1 * 8 + fl];
    if (o2 < c) a2 = xg4[(size_t)j2 * 8 + fl];
    if (o3 < c) a3 = xg4[(size_t)j3 * 8 + fl];
    for (int o = 32 + es; o < c; o += 8) {     // rare long tail (deg > 32)
        int j = edgeSrc[s + o];
        float4 v = xg4[(size_t)j * 8 + fl];
        a0.x += v.x; a0.y += v.y; a0.z += v.z; a0.w += v.w;
    }
    float4 A;
    A.x = (a0.x + a1.x) + (a2.x + a3.x);
    A.y = (a0.y + a1.y) + (a2.y + a3.y);
    A.z = (a0.z + a1.z) + (a2.z + a3.z);
    A.w = (a0.w + a1.w) + (a2.w + a3.w);
#pragma unroll
    for (int m = 8; m <= 32; m <<= 1) {
        A.x += __shfl_xor(A.x, m);
        A.y += __shfl_xor(A.y, m);
        A.z += __shfl_xor(A.z, m);
        A.w += __shfl_xor(A.w, m);
    }
    if (es == 0) {
        float4 sl = xg4[(size_t)node * 8 + fl];   // self-loop
        A.x += sl.x; A.y += sl.y; A.z += sl.z; A.w += sl.w;
        s4[(size_t)node * 8 + fl] = A;
    }
}

// ---- dense per-node MLP (one node per lane, zero LDS/shfl) ------------------
__global__ void k_gemm12(const float* __restrict__ sIn, const float* __restrict__ dinv,
                         const float* __restrict__ b1, const float* __restrict__ W1,
                         const float* __restrict__ W2, float* __restrict__ g2, int N) {
    int node = blockIdx.x * blockDim.x + threadIdx.x;
    if (node >= N) return;

    float sv[DIN];
    const float4* s4 = (const float4*)sIn;
#pragma unroll
    for (int q = 0; q < 8; ++q) {
        float4 v = s4[(size_t)node * 8 + q];
        sv[4 * q + 0] = v.x; sv[4 * q + 1] = v.y;
        sv[4 * q + 2] = v.z; sv[4 * q + 3] = v.w;
    }
    float h[DH];
#pragma unroll
    for (int k = 0; k < DH; ++k) h[k] = 0.f;
#pragma unroll
    for (int d = 0; d < DIN; ++d) {
#pragma unroll
        for (int k = 0; k < DH; ++k) h[k] += sv[d] * W1[d * DH + k];
    }
    float di = dinv[node];
#pragma unroll
    for (int k = 0; k < DH; ++k) h[k] = fmaxf(di * h[k] + b1[k], 0.f);
    float g[DOUT];
#pragma unroll
    for (int k = 0; k < DOUT; ++k) g[k] = 0.f;
#pragma unroll
    for (int d = 0; d < DH; ++d) {
#pragma unroll
        for (int k = 0; k < DOUT; ++k) g[k] += h[d] * W2[d * DOUT + k];
    }
    float4* g2_4 = (float4*)g2;
#pragma unroll
    for (int q = 0; q < 4; ++q) {
        float4 r;
        r.x = di * g[4 * q + 0]; r.y = di * g[4 * q + 1];
        r.z = di * g[4 * q + 2]; r.w = di * g[4 * q + 3];
        g2_4[(size_t)node * 4 + q] = r;
    }
}

// ---- layer-2 aggregate + finalize -------------------------------------------
__global__ void k_agg2(const int* __restrict__ rowStart, const int* __restrict__ deg,
                       const int* __restrict__ edgeSrc, const float4* __restrict__ g2_4,
                       const float* __restrict__ dinv, const float* __restrict__ b2,
                       float4* __restrict__ out4, int N) {
    int tid = threadIdx.x;
    int w = tid >> 6, lane = tid & 63;
    int es = lane >> 2, fl = lane & 3;
    int node = blockIdx.x * 4 + w;   // wave-uniform
    if (node >= N) return;

    int s = rowStart[node], c = deg[node];
    float4 a0 = {0,0,0,0}, a1 = {0,0,0,0};
    int j0 = 0, j1 = 0;
    int o0 = es, o1 = 16 + es;
    if (o0 < c) j0 = edgeSrc[s + o0];
    if (o1 < c) j1 = edgeSrc[s + o1];
    if (o0 < c) a0 = g2_4[(size_t)j0 * 4 + fl];
    if (o1 < c) a1 = g2_4[(size_t)j1 * 4 + fl];
    for (int o = 32 + es; o < c; o += 16) {
        int j = edgeSrc[s + o];
        float4 v = g2_4[(size_t)j * 4 + fl];
        a0.x += v.x; a0.y += v.y; a0.z += v.z; a0.w += v.w;
    }
    float4 A;
    A.x = a0.x + a1.x; A.y = a0.y + a1.y; A.z = a0.z + a1.z; A.w = a0.w + a1.w;
#pragma unroll
    for (int m = 4; m <= 32; m <<= 1) {
        A.x += __shfl_xor(A.x, m);
        A.y += __shfl_xor(A.y, m);
        A.z += __shfl_xor(A.z, m);
        A.w += __shfl_xor(A.w, m);
    }
    if (es == 0) {
        float4 sl = g2_4[(size_t)node * 4 + fl];  // self-loop
        A.x += sl.x; A.y += sl.y; A.z += sl.z; A.w += sl.w;
        float d = dinv[node];
        const float4* b2_4 = (const float4*)b2;
        float4 bq = b2_4[fl], r;
        r.x = d * A.x + bq.x; r.y = d * A.y + bq.y;
        r.z = d * A.z + bq.z; r.w = d * A.w + bq.w;
        out4[(size_t)node * 4 + fl] = r;
    }
}

// ----------------------------------------------------------------------------
static inline size_t align16(size_t v) { return (v + 15) & ~(size_t)15; }

extern "C" void kernel_launch(void* const* d_in, const int* in_sizes, int n_in,
                              void* d_out, int out_size, void* d_ws, size_t ws_size,
                              hipStream_t stream) {
    const float* x  = (const float*)d_in[0];
    const int*   ei = (const int*)  d_in[1];
    const float* W1 = (const float*)d_in[2];
    const float* b1 = (const float*)d_in[3];
    const float* W2 = (const float*)d_in[4];
    const float* b2 = (const float*)d_in[5];

    int N = in_sizes[0] / DIN;
    int E = in_sizes[1] / 2;
    const int* src = ei;
    const int* dst = ei + E;
    int NBKT = (N + BKT_NODES - 1) >> BKT_SHIFT;   // 196 for N=100k (<= MAXBKT)

    // workspace layout, 16B-aligned regions
    char* base = (char*)d_ws;
    size_t off = 0;
    int*   hist       = (int*)(base + off);   off = align16(off + (size_t)MAXBKT * PBLK * 4);
    int*   bucketBase = (int*)(base + off);   off = align16(off + (size_t)(MAXBKT + 1) * 4);
    int*   rowStart   = (int*)(base + off);   off = align16(off + (size_t)N * 4);
    int*   deg        = (int*)(base + off);   off = align16(off + (size_t)N * 4);
    float* dinv       = (float*)(base + off); off = align16(off + (size_t)N * 4);
    int*   edgeSrc    = (int*)(base + off);   off = align16(off + (size_t)E * 4);
    float* xg         = (float*)(base + off); off = align16(off + (size_t)N * DIN * 4);
    float* sagg       = (float*)(base + off); off = align16(off + (size_t)N * DIN * 4);
    float* g2         = (float*)(base + off); off = align16(off + (size_t)N * DOUT * 4);
    // packed pairs (E*4B = 6.4MB) aliases sagg (12.8MB): pairs dead after
    // k_build; sagg first written by k_agg1 (later on same stream)
    unsigned* pairs   = (unsigned*)sagg;

    k_hist    <<<PBLK, 256, 0, stream>>>(dst, hist, E, NBKT);
    k_scanhist<<<1, 1024, 0, stream>>>(hist, bucketBase, NBKT * PBLK, NBKT, E);
    k_part    <<<PBLK, 256, 0, stream>>>(src, dst, hist, pairs, E, NBKT);
    k_build   <<<NBKT, BKT_NODES, 0, stream>>>(pairs, bucketBase, rowStart, deg,
                                               dinv, edgeSrc, (const float4*)x,
                                               (float4*)xg, N, NBKT);

    k_agg1<<<(N + 3) / 4, 256, 0, stream>>>(rowStart, deg, edgeSrc,
                                            (const float4*)xg, (float4*)sagg, N);
    k_gemm12<<<(N + 255) / 256, 256, 0, stream>>>(sagg, dinv, b1, W1, W2, g2, N);
    k_agg2<<<(N + 3) / 4, 256, 0, stream>>>(rowStart, deg, edgeSrc,
                                            (const float4*)g2, dinv, b2,
                                            (float4*)d_out, N);
}

// Round 14
// 227.979 us; speedup vs baseline: 1.3007x; 1.3007x over previous
//
#include <hip/hip_runtime.h>

#define DIN  32
#define DH   64
#define DOUT 16
#define BKT_SHIFT 9         // 512 nodes per bucket
#define BKT_NODES 512
#define MAXBKT 256          // supports N <= 131072 (also needed for 17-bit src pack)
#define PBLK 256            // partition blocks (hist/part grids must match)
#define SRC_BITS 17
#define SRC_MASK ((1u << SRC_BITS) - 1u)
#define SCAN_BLK 1024       // elements per scanA block

// ---- 1. per-block LDS histogram of dst buckets ------------------------------
__global__ void k_hist(const int* __restrict__ dst, int* __restrict__ hist,
                       int E, int NBKT) {
    __shared__ int h[MAXBKT];
    int tid = threadIdx.x;
    for (int i = tid; i < NBKT; i += blockDim.x) h[i] = 0;
    __syncthreads();
    int nth = gridDim.x * blockDim.x;
    int EV = E >> 2;
    const int4* d4p = (const int4*)dst;
    for (int v = blockIdx.x * blockDim.x + tid; v < EV; v += nth) {
        int4 d = d4p[v];
        atomicAdd(&h[d.x >> BKT_SHIFT], 1);
        atomicAdd(&h[d.y >> BKT_SHIFT], 1);
        atomicAdd(&h[d.z >> BKT_SHIFT], 1);
        atomicAdd(&h[d.w >> BKT_SHIFT], 1);
    }
    if (blockIdx.x == 0 && tid < (E & 3))
        atomicAdd(&h[dst[(E & ~3) + tid] >> BKT_SHIFT], 1);
    __syncthreads();
    for (int i = tid; i < NBKT; i += blockDim.x)
        hist[i * PBLK + blockIdx.x] = h[i];
}

// ---- 2a. hierarchical scan of hist: per-1024-block scan ---------------------
__global__ void k_scanA(const int* __restrict__ arr, int* __restrict__ partial,
                        int* __restrict__ blockSums, int total) {
    __shared__ int s[256];
    int tid  = threadIdx.x;
    int base = blockIdx.x * SCAN_BLK + tid * 4;
    int v0 = (base + 0 < total) ? arr[base + 0] : 0;
    int v1 = (base + 1 < total) ? arr[base + 1] : 0;
    int v2 = (base + 2 < total) ? arr[base + 2] : 0;
    int v3 = (base + 3 < total) ? arr[base + 3] : 0;
    int tot = v0 + v1 + v2 + v3;
    s[tid] = tot;
    __syncthreads();
    for (int off = 1; off < 256; off <<= 1) {
        int t = (tid >= off) ? s[tid - off] : 0;
        __syncthreads();
        s[tid] += t;
        __syncthreads();
    }
    int excl = s[tid] - tot;
    if (base + 0 < total) partial[base + 0] = excl;
    if (base + 1 < total) partial[base + 1] = excl + v0;
    if (base + 2 < total) partial[base + 2] = excl + v0 + v1;
    if (base + 3 < total) partial[base + 3] = excl + v0 + v1 + v2;
    if (tid == 255) blockSums[blockIdx.x] = s[255];
}

// ---- 2b. scan the block sums (one tiny block) -------------------------------
__global__ void k_scanB(int* __restrict__ blockSums, int* __restrict__ blockOff,
                        int NB) {
    __shared__ int s[256];
    int tid = threadIdx.x;
    int v = (tid < NB) ? blockSums[tid] : 0;
    s[tid] = v;
    __syncthreads();
    for (int off = 1; off < 256; off <<= 1) {
        int t = (tid >= off) ? s[tid - off] : 0;
        __syncthreads();
        s[tid] += t;
        __syncthreads();
    }
    if (tid < NB) blockOff[tid] = s[tid] - v;
}

// ---- 2c. finalize: hist = partial + blockOff; extract bucketBase ------------
__global__ void k_scanC(const int* __restrict__ partial, const int* __restrict__ blockOff,
                        int* __restrict__ hist, int* __restrict__ bucketBase,
                        int total, int NBKT, int E) {
    int i = blockIdx.x * blockDim.x + threadIdx.x;
    if (i < total) {
        int v = partial[i] + blockOff[i / SCAN_BLK];
        hist[i] = v;
        if ((i & (PBLK - 1)) == 0) bucketBase[i / PBLK] = v;
    }
    if (i == 0) bucketBase[NBKT] = E;
}

// ---- 3. partition PACKED pairs into buckets via block-private LDS cursors ---
// pack = (dst & 511) << 17 | src  (4B/edge). Each (block,bucket) subrange is
// private -> frontier lines on one CU/XCD, filled within the block's pass.
__global__ void k_part(const int* __restrict__ src, const int* __restrict__ dst,
                       const int* __restrict__ hist, unsigned* __restrict__ pairs,
                       int E, int NBKT) {
    __shared__ int cur[MAXBKT];
    int tid = threadIdx.x;
    for (int i = tid; i < NBKT; i += blockDim.x)
        cur[i] = hist[i * PBLK + blockIdx.x];
    __syncthreads();
    int nth = gridDim.x * blockDim.x;
    int EV = E >> 2;
    const int4* d4p = (const int4*)dst;
    const int4* s4p = (const int4*)src;
    for (int v = blockIdx.x * blockDim.x + tid; v < EV; v += nth) {
        int4 d = d4p[v];
        int4 s = s4p[v];
        int p;
        p = atomicAdd(&cur[d.x >> BKT_SHIFT], 1);
        pairs[p] = ((unsigned)(d.x & (BKT_NODES - 1)) << SRC_BITS) | (unsigned)s.x;
        p = atomicAdd(&cur[d.y >> BKT_SHIFT], 1);
        pairs[p] = ((unsigned)(d.y & (BKT_NODES - 1)) << SRC_BITS) | (unsigned)s.y;
        p = atomicAdd(&cur[d.z >> BKT_SHIFT], 1);
        pairs[p] = ((unsigned)(d.z & (BKT_NODES - 1)) << SRC_BITS) | (unsigned)s.z;
        p = atomicAdd(&cur[d.w >> BKT_SHIFT], 1);
        pairs[p] = ((unsigned)(d.w & (BKT_NODES - 1)) << SRC_BITS) | (unsigned)s.w;
    }
    if (blockIdx.x == 0 && tid < (E & 3)) {
        int e = (E & ~3) + tid;
        int d = dst[e];
        int p = atomicAdd(&cur[d >> BKT_SHIFT], 1);
        pairs[p] = ((unsigned)(d & (BKT_NODES - 1)) << SRC_BITS) | (unsigned)src[e];
    }
}

// ---- 4. per-bucket CSR finalize + fused xg scale ----------------------------
__global__ void k_build(const unsigned* __restrict__ pairs,
                        const int* __restrict__ bucketBase,
                        int* __restrict__ rowStart, int* __restrict__ deg,
                        float* __restrict__ dinv, int* __restrict__ edgeSrc,
                        const float4* __restrict__ x4, float4* __restrict__ xg4,
                        int N, int NBKT) {
    __shared__ int cnt[BKT_NODES];   // counts (kept for deg/dinv/xg)
    __shared__ int loc[BKT_NODES];   // start offsets -> reused as cursors
    __shared__ int s[BKT_NODES];     // scan
    int b = blockIdx.x;
    int n_lo = b << BKT_SHIFT;
    int nNodes = min(N - n_lo, BKT_NODES);
    int segBase = bucketBase[b];
    int segLen  = bucketBase[b + 1] - segBase;
    int tid = threadIdx.x;   // blockDim = BKT_NODES (512)

    cnt[tid] = 0;
    __syncthreads();
    for (int t = tid; t < segLen; t += BKT_NODES)
        atomicAdd(&cnt[pairs[segBase + t] >> SRC_BITS], 1);
    __syncthreads();
    int c = cnt[tid];
    s[tid] = c;
    __syncthreads();
    for (int off = 1; off < BKT_NODES; off <<= 1) {
        int t = (tid >= off) ? s[tid - off] : 0;
        __syncthreads();
        s[tid] += t;
        __syncthreads();
    }
    loc[tid] = s[tid] - c;
    if (tid < nNodes) {
        rowStart[n_lo + tid] = segBase + (s[tid] - c);
        deg[n_lo + tid]      = c;
        dinv[n_lo + tid]     = rsqrtf((float)c + 1.0f);  // +1 self-loop
    }
    __syncthreads();
    // fused xg scale: this bucket's x slab (block-local 64KB stream)
    for (int i = tid; i < nNodes * 8; i += BKT_NODES) {
        float dv = rsqrtf((float)cnt[i >> 3] + 1.0f);
        float4 v = x4[(size_t)n_lo * 8 + i];
        v.x *= dv; v.y *= dv; v.z *= dv; v.w *= dv;
        xg4[(size_t)n_lo * 8 + i] = v;
    }
    // place edges within the block-private window (loc doubles as cursor)
    for (int t = tid; t < segLen; t += BKT_NODES) {
        unsigned pk = pairs[segBase + t];
        int p = atomicAdd(&loc[pk >> SRC_BITS], 1);
        edgeSrc[segBase + p] = (int)(pk & SRC_MASK);
    }
}

// ---- layer-1 aggregation: s_i = sum_j xg_j + xg_i ---------------------------
// wave per node. lane = es*8 + fl. Two-stage predicated block (2 latency hops).
__global__ void k_agg1(const int* __restrict__ rowStart, const int* __restrict__ deg,
                       const int* __restrict__ edgeSrc, const float4* __restrict__ xg4,
                       float4* __restrict__ s4, int N) {
    int tid = threadIdx.x;
    int w = tid >> 6, lane = tid & 63;
    int es = lane >> 3, fl = lane & 7;
    int node = blockIdx.x * 4 + w;   // wave-uniform
    if (node >= N) return;

    int s = rowStart[node], c = deg[node];
    float4 a0 = {0,0,0,0}, a1 = {0,0,0,0}, a2 = {0,0,0,0}, a3 = {0,0,0,0};
    int j0 = 0, j1 = 0, j2 = 0, j3 = 0;
    int o0 = es, o1 = 8 + es, o2 = 16 + es, o3 = 24 + es;
    if (o0 < c) j0 = edgeSrc[s + o0];
    if (o1 < c) j1 = edgeSrc[s + o1];
    if (o2 < c) j2 = edgeSrc[s + o2];
    if (o3 < c) j3 = edgeSrc[s + o3];
    if (o0 < c) a0 = xg4[(size_t)j0 * 8 + fl];
    if (o1 < c) a1 = xg4[(size_t)j1 * 8 + fl];
    if (o2 < c) a2 = xg4[(size_t)j2 * 8 + fl];
    if (o3 < c) a3 = xg4[(size_t)j3 * 8 + fl];
    for (int o = 32 + es; o < c; o += 8) {     // rare long tail (deg > 32)
        int j = edgeSrc[s + o];
        float4 v = xg4[(size_t)j * 8 + fl];
        a0.x += v.x; a0.y += v.y; a0.z += v.z; a0.w += v.w;
    }
    float4 A;
    A.x = (a0.x + a1.x) + (a2.x + a3.x);
    A.y = (a0.y + a1.y) + (a2.y + a3.y);
    A.z = (a0.z + a1.z) + (a2.z + a3.z);
    A.w = (a0.w + a1.w) + (a2.w + a3.w);
#pragma unroll
    for (int m = 8; m <= 32; m <<= 1) {
        A.x += __shfl_xor(A.x, m);
        A.y += __shfl_xor(A.y, m);
        A.z += __shfl_xor(A.z, m);
        A.w += __shfl_xor(A.w, m);
    }
    if (es == 0) {
        float4 sl = xg4[(size_t)node * 8 + fl];   // self-loop
        A.x += sl.x; A.y += sl.y; A.z += sl.z; A.w += sl.w;
        s4[(size_t)node * 8 + fl] = A;
    }
}

// ---- dense per-node MLP (one node per lane, zero LDS/shfl) ------------------
__global__ void k_gemm12(const float* __restrict__ sIn, const float* __restrict__ dinv,
                         const float* __restrict__ b1, const float* __restrict__ W1,
                         const float* __restrict__ W2, float* __restrict__ g2, int N) {
    int node = blockIdx.x * blockDim.x + threadIdx.x;
    if (node >= N) return;

    float sv[DIN];
    const float4* s4 = (const float4*)sIn;
#pragma unroll
    for (int q = 0; q < 8; ++q) {
        float4 v = s4[(size_t)node * 8 + q];
        sv[4 * q + 0] = v.x; sv[4 * q + 1] = v.y;
        sv[4 * q + 2] = v.z; sv[4 * q + 3] = v.w;
    }
    float h[DH];
#pragma unroll
    for (int k = 0; k < DH; ++k) h[k] = 0.f;
#pragma unroll
    for (int d = 0; d < DIN; ++d) {
#pragma unroll
        for (int k = 0; k < DH; ++k) h[k] += sv[d] * W1[d * DH + k];
    }
    float di = dinv[node];
#pragma unroll
    for (int k = 0; k < DH; ++k) h[k] = fmaxf(di * h[k] + b1[k], 0.f);
    float g[DOUT];
#pragma unroll
    for (int k = 0; k < DOUT; ++k) g[k] = 0.f;
#pragma unroll
    for (int d = 0; d < DH; ++d) {
#pragma unroll
        for (int k = 0; k < DOUT; ++k) g[k] += h[d] * W2[d * DOUT + k];
    }
    float4* g2_4 = (float4*)g2;
#pragma unroll
    for (int q = 0; q < 4; ++q) {
        float4 r;
        r.x = di * g[4 * q + 0]; r.y = di * g[4 * q + 1];
        r.z = di * g[4 * q + 2]; r.w = di * g[4 * q + 3];
        g2_4[(size_t)node * 4 + q] = r;
    }
}

// ---- layer-2 aggregate + finalize -------------------------------------------
__global__ void k_agg2(const int* __restrict__ rowStart, const int* __restrict__ deg,
                       const int* __restrict__ edgeSrc, const float4* __restrict__ g2_4,
                       const float* __restrict__ dinv, const float* __restrict__ b2,
                       float4* __restrict__ out4, int N) {
    int tid = threadIdx.x;
    int w = tid >> 6, lane = tid & 63;
    int es = lane >> 2, fl = lane & 3;
    int node = blockIdx.x * 4 + w;   // wave-uniform
    if (node >= N) return;

    int s = rowStart[node], c = deg[node];
    float4 a0 = {0,0,0,0}, a1 = {0,0,0,0};
    int j0 = 0, j1 = 0;
    int o0 = es, o1 = 16 + es;
    if (o0 < c) j0 = edgeSrc[s + o0];
    if (o1 < c) j1 = edgeSrc[s + o1];
    if (o0 < c) a0 = g2_4[(size_t)j0 * 4 + fl];
    if (o1 < c) a1 = g2_4[(size_t)j1 * 4 + fl];
    for (int o = 32 + es; o < c; o += 16) {
        int j = edgeSrc[s + o];
        float4 v = g2_4[(size_t)j * 4 + fl];
        a0.x += v.x; a0.y += v.y; a0.z += v.z; a0.w += v.w;
    }
    float4 A;
    A.x = a0.x + a1.x; A.y = a0.y + a1.y; A.z = a0.z + a1.z; A.w = a0.w + a1.w;
#pragma unroll
    for (int m = 4; m <= 32; m <<= 1) {
        A.x += __shfl_xor(A.x, m);
        A.y += __shfl_xor(A.y, m);
        A.z += __shfl_xor(A.z, m);
        A.w += __shfl_xor(A.w, m);
    }
    if (es == 0) {
        float4 sl = g2_4[(size_t)node * 4 + fl];  // self-loop
        A.x += sl.x; A.y += sl.y; A.z += sl.z; A.w += sl.w;
        float d = dinv[node];
        const float4* b2_4 = (const float4*)b2;
        float4 bq = b2_4[fl], r;
        r.x = d * A.x + bq.x; r.y = d * A.y + bq.y;
        r.z = d * A.z + bq.z; r.w = d * A.w + bq.w;
        out4[(size_t)node * 4 + fl] = r;
    }
}

// ----------------------------------------------------------------------------
static inline size_t align16(size_t v) { return (v + 15) & ~(size_t)15; }

extern "C" void kernel_launch(void* const* d_in, const int* in_sizes, int n_in,
                              void* d_out, int out_size, void* d_ws, size_t ws_size,
                              hipStream_t stream) {
    const float* x  = (const float*)d_in[0];
    const int*   ei = (const int*)  d_in[1];
    const float* W1 = (const float*)d_in[2];
    const float* b1 = (const float*)d_in[3];
    const float* W2 = (const float*)d_in[4];
    const float* b2 = (const float*)d_in[5];

    int N = in_sizes[0] / DIN;
    int E = in_sizes[1] / 2;
    const int* src = ei;
    const int* dst = ei + E;
    int NBKT = (N + BKT_NODES - 1) >> BKT_SHIFT;   // 196 for N=100k (<= MAXBKT)
    int total = NBKT * PBLK;                       // hist elements (50176)
    int NSB = (total + SCAN_BLK - 1) / SCAN_BLK;   // scanA blocks (<= 256)

    // workspace layout, 16B-aligned regions
    char* base = (char*)d_ws;
    size_t off = 0;
    int*   hist       = (int*)(base + off);   off = align16(off + (size_t)MAXBKT * PBLK * 4);
    int*   partial    = (int*)(base + off);   off = align16(off + (size_t)MAXBKT * PBLK * 4);
    int*   blockSums  = (int*)(base + off);   off = align16(off + 256 * 4);
    int*   blockOff   = (int*)(base + off);   off = align16(off + 256 * 4);
    int*   bucketBase = (int*)(base + off);   off = align16(off + (size_t)(MAXBKT + 1) * 4);
    int*   rowStart   = (int*)(base + off);   off = align16(off + (size_t)N * 4);
    int*   deg        = (int*)(base + off);   off = align16(off + (size_t)N * 4);
    float* dinv       = (float*)(base + off); off = align16(off + (size_t)N * 4);
    int*   edgeSrc    = (int*)(base + off);   off = align16(off + (size_t)E * 4);
    float* xg         = (float*)(base + off); off = align16(off + (size_t)N * DIN * 4);
    float* sagg       = (float*)(base + off); off = align16(off + (size_t)N * DIN * 4);
    float* g2         = (float*)(base + off); off = align16(off + (size_t)N * DOUT * 4);
    // packed pairs (E*4B = 6.4MB) aliases sagg (12.8MB): pairs dead after
    // k_build; sagg first written by k_agg1 (later on same stream)
    unsigned* pairs   = (unsigned*)sagg;

    k_hist <<<PBLK, 256, 0, stream>>>(dst, hist, E, NBKT);
    k_scanA<<<NSB, 256, 0, stream>>>(hist, partial, blockSums, total);
    k_scanB<<<1, 256, 0, stream>>>(blockSums, blockOff, NSB);
    k_scanC<<<(total + 255) / 256, 256, 0, stream>>>(partial, blockOff, hist,
                                                     bucketBase, total, NBKT, E);
    k_part <<<PBLK, 256, 0, stream>>>(src, dst, hist, pairs, E, NBKT);
    k_build<<<NBKT, BKT_NODES, 0, stream>>>(pairs, bucketBase, rowStart, deg,
                                            dinv, edgeSrc, (const float4*)x,
                                            (float4*)xg, N, NBKT);

    k_agg1<<<(N + 3) / 4, 256, 0, stream>>>(rowStart, deg, edgeSrc,
                                            (const float4*)xg, (float4*)sagg, N);
    k_gemm12<<<(N + 255) / 256, 256, 0, stream>>>(sagg, dinv, b1, W1, W2, g2, N);
    k_agg2<<<(N + 3) / 4, 256, 0, stream>>>(rowStart, deg, edgeSrc,
                                            (const float4*)g2, dinv, b2,
                                            (float4*)d_out, N);
}